// Round 1
// baseline (3402.836 us; speedup 1.0000x reference)
//
#include <hip/hip_runtime.h>
#include <cstdint>

typedef __bf16  bf16x8  __attribute__((ext_vector_type(8)));
typedef short   short8v __attribute__((ext_vector_type(8)));
typedef float   f32x4   __attribute__((ext_vector_type(4)));

constexpr int N  = 262144;
constexpr int C  = 128;
constexpr int K  = 27;
constexpr int M  = 131072;
constexpr int BR = 64;                    // rows per conv block
constexpr int TILES_PER_K = M / BR;       // 2048

__device__ __forceinline__ uint16_t f2bf(float f) {
    union { float f; uint32_t u; } x; x.f = f;
    uint32_t r = (x.u + 0x7FFFu + ((x.u >> 16) & 1u)) >> 16;  // RNE
    return (uint16_t)r;
}

// ---------- prep: feats f32 -> bf16 ----------
__global__ __launch_bounds__(256) void cast_feats_kernel(
    const float* __restrict__ in, uint16_t* __restrict__ out) {
    int i = blockIdx.x * 256 + threadIdx.x;        // 8 elems per thread
    const float4* src = reinterpret_cast<const float4*>(in) + (size_t)i * 2;
    float4 a = src[0], b = src[1];
    union { uint16_t u[8]; short8v v; } r;
    r.u[0]=f2bf(a.x); r.u[1]=f2bf(a.y); r.u[2]=f2bf(a.z); r.u[3]=f2bf(a.w);
    r.u[4]=f2bf(b.x); r.u[5]=f2bf(b.y); r.u[6]=f2bf(b.z); r.u[7]=f2bf(b.w);
    *(reinterpret_cast<short8v*>(out) + i) = r.v;
}

// ---------- prep: W[k][cin][cout] f32 -> WT[k][cout][cin] bf16 (both convs) ----------
__global__ __launch_bounds__(256) void transpose_w_kernel(
    const float* __restrict__ W1, const float* __restrict__ W2,
    uint16_t* __restrict__ WT1, uint16_t* __restrict__ WT2) {
    int i = blockIdx.x * 256 + threadIdx.x;        // over K*C*C = 442368
    int k    = i / (C * C);
    int rem  = i - k * (C * C);
    int cout = rem >> 7;
    int cin  = rem & 127;
    int src  = k * C * C + cin * C + cout;
    WT1[i] = f2bf(W1[src]);
    WT2[i] = f2bf(W2[src]);
}

// ---------- sparse conv: gather -> MFMA GEMM -> atomic scatter-add ----------
__global__ __launch_bounds__(256, 3) void conv_kernel(
    const uint16_t* __restrict__ featsB,   // [N][C] bf16
    const uint16_t* __restrict__ WT,       // [K][Cout][Cin] bf16
    const int* __restrict__ in_maps,       // [K][M]
    const int* __restrict__ out_maps,      // [K][M]
    float* __restrict__ out)               // [N][C] f32 accumulator
{
    __shared__ char lds[BR * C * 2 + C * C * 2];   // A 16KB + W 32KB = 48KB
    char* Alds = lds;
    char* Wlds = lds + BR * C * 2;

    const int tile = blockIdx.x;
    const int k    = tile / TILES_PER_K;
    const int m0   = (tile % TILES_PER_K) * BR;
    const int tid  = threadIdx.x;

    // stage A: gather 64 rows x 128ch bf16 (1024 16B-chunks), XOR-swizzled
    {
        const int* im = in_maps + k * M + m0;
        #pragma unroll
        for (int i = 0; i < 4; ++i) {
            int chunk = tid + 256 * i;
            int row   = chunk >> 4;
            int c8    = chunk & 15;
            int g     = im[row];
            short8v v = *reinterpret_cast<const short8v*>(featsB + g * C + c8 * 8);
            int off = (row * 256 + c8 * 16) ^ ((row & 7) << 4);
            *reinterpret_cast<short8v*>(Alds + off) = v;
        }
        // stage W[k]: 128x128 bf16 (2048 chunks), swizzled on cout
        const uint16_t* w = WT + k * C * C;
        #pragma unroll
        for (int i = 0; i < 8; ++i) {
            int chunk = tid + 256 * i;
            int cout  = chunk >> 4;
            int c8    = chunk & 15;
            short8v v = *reinterpret_cast<const short8v*>(w + chunk * 8);
            int off = (cout * 256 + c8 * 16) ^ ((cout & 7) << 4);
            *reinterpret_cast<short8v*>(Wlds + off) = v;
        }
    }
    __syncthreads();

    const int wave  = tid >> 6;
    const int lane  = tid & 63;
    const int r16   = lane & 15;     // A-row / B-col / D-col within 16-tile
    const int khalf = lane >> 4;     // k-group 0..3

    // A fragments: rows 16*wave + r16, k = kk*32 + khalf*8 + [0..7]
    short8v a[4];
    {
        int row  = wave * 16 + r16;
        int base = row * 256;
        int swz  = (row & 7) << 4;
        #pragma unroll
        for (int kk = 0; kk < 4; ++kk)
            a[kk] = *reinterpret_cast<const short8v*>(Alds + ((base + kk * 64 + khalf * 16) ^ swz));
    }

    f32x4 acc[8];
    #pragma unroll
    for (int t = 0; t < 8; ++t) acc[t] = (f32x4){0.f, 0.f, 0.f, 0.f};

    #pragma unroll
    for (int t = 0; t < 8; ++t) {
        int col  = t * 16 + r16;
        int base = col * 256;
        int swz  = (col & 7) << 4;
        #pragma unroll
        for (int kk = 0; kk < 4; ++kk) {
            short8v b = *reinterpret_cast<const short8v*>(Wlds + ((base + kk * 64 + khalf * 16) ^ swz));
            acc[t] = __builtin_amdgcn_mfma_f32_16x16x32_bf16(
                __builtin_bit_cast(bf16x8, a[kk]), __builtin_bit_cast(bf16x8, b), acc[t], 0, 0, 0);
        }
    }

    // scatter-add: D layout col=lane&15, row=(lane>>4)*4+reg
    const int* om = out_maps + k * M + m0 + wave * 16;
    #pragma unroll
    for (int j = 0; j < 4; ++j) {
        int g = om[khalf * 4 + j];
        float* dst = out + g * C + r16;
        #pragma unroll
        for (int t = 0; t < 8; ++t)
            unsafeAtomicAdd(dst + t * 16, acc[t][j]);
    }
}

// ---------- per-channel sum & sumsq ----------
__global__ __launch_bounds__(256) void stats_kernel(
    const float* __restrict__ x, float* __restrict__ sums) {   // sums[0..C)=sum, [C..2C)=sumsq
    const int tid = threadIdx.x;
    const int c32 = tid & 31;           // float4 column group
    const int rg  = tid >> 5;           // 0..7
    constexpr int RPB = N / 1024;       // 256 rows per block
    float4 s = {0,0,0,0}, q = {0,0,0,0};
    const float* base = x + (size_t)blockIdx.x * RPB * C + c32 * 4;
    for (int r = rg; r < RPB; r += 8) {
        float4 v = *reinterpret_cast<const float4*>(base + r * C);
        s.x += v.x; s.y += v.y; s.z += v.z; s.w += v.w;
        q.x += v.x*v.x; q.y += v.y*v.y; q.z += v.z*v.z; q.w += v.w*v.w;
    }
    __shared__ float4 red[8][32];
    red[rg][c32] = s;
    __syncthreads();
    if (rg == 0) {
        float4 t = red[0][c32];
        #pragma unroll
        for (int j = 1; j < 8; ++j) { float4 u = red[j][c32]; t.x+=u.x; t.y+=u.y; t.z+=u.z; t.w+=u.w; }
        unsafeAtomicAdd(&sums[c32*4+0], t.x); unsafeAtomicAdd(&sums[c32*4+1], t.y);
        unsafeAtomicAdd(&sums[c32*4+2], t.z); unsafeAtomicAdd(&sums[c32*4+3], t.w);
    }
    __syncthreads();
    red[rg][c32] = q;
    __syncthreads();
    if (rg == 0) {
        float4 t = red[0][c32];
        #pragma unroll
        for (int j = 1; j < 8; ++j) { float4 u = red[j][c32]; t.x+=u.x; t.y+=u.y; t.z+=u.z; t.w+=u.w; }
        unsafeAtomicAdd(&sums[C+c32*4+0], t.x); unsafeAtomicAdd(&sums[C+c32*4+1], t.y);
        unsafeAtomicAdd(&sums[C+c32*4+2], t.z); unsafeAtomicAdd(&sums[C+c32*4+3], t.w);
    }
}

// ---------- BN finalize: scale/shift per channel ----------
__global__ void finalize_kernel(const float* __restrict__ sums,
                                const float* __restrict__ gamma, const float* __restrict__ beta,
                                float* __restrict__ ss) {       // ss[0..C)=scale, [C..2C)=shift
    int c = threadIdx.x;
    float m  = sums[c] * (1.0f / N);
    float v  = sums[C + c] * (1.0f / N) - m * m;
    float r  = rsqrtf(v + 1e-5f);
    float sc = gamma[c] * r;
    ss[c]     = sc;
    ss[C + c] = beta[c] - m * sc;
}

// ---------- BN1 + ReLU + cast to bf16 ----------
__global__ __launch_bounds__(256) void bnrelu_kernel(
    const float* __restrict__ x, const float* __restrict__ ss, uint16_t* __restrict__ out) {
    int i = blockIdx.x * 256 + threadIdx.x;      // 8 elems per thread
    int base = i * 8;
    int c = base & 127;
    float4 sc0 = *reinterpret_cast<const float4*>(ss + c);
    float4 sc1 = *reinterpret_cast<const float4*>(ss + c + 4);
    float4 sh0 = *reinterpret_cast<const float4*>(ss + C + c);
    float4 sh1 = *reinterpret_cast<const float4*>(ss + C + c + 4);
    const float4* src = reinterpret_cast<const float4*>(x + base);
    float4 a = src[0], b = src[1];
    union { uint16_t u[8]; short8v v; } r;
    r.u[0] = f2bf(fmaxf(fmaf(a.x, sc0.x, sh0.x), 0.f));
    r.u[1] = f2bf(fmaxf(fmaf(a.y, sc0.y, sh0.y), 0.f));
    r.u[2] = f2bf(fmaxf(fmaf(a.z, sc0.z, sh0.z), 0.f));
    r.u[3] = f2bf(fmaxf(fmaf(a.w, sc0.w, sh0.w), 0.f));
    r.u[4] = f2bf(fmaxf(fmaf(b.x, sc1.x, sh1.x), 0.f));
    r.u[5] = f2bf(fmaxf(fmaf(b.y, sc1.y, sh1.y), 0.f));
    r.u[6] = f2bf(fmaxf(fmaf(b.z, sc1.z, sh1.z), 0.f));
    r.u[7] = f2bf(fmaxf(fmaf(b.w, sc1.w, sh1.w), 0.f));
    *(reinterpret_cast<short8v*>(out) + i) = r.v;
}

// ---------- BN2 + residual + ReLU (in place on d_out) ----------
__global__ __launch_bounds__(256) void final_kernel(
    float* __restrict__ x, const float* __restrict__ feats, const float* __restrict__ ss) {
    int i = blockIdx.x * 256 + threadIdx.x;      // 4 elems per thread
    int base = i * 4;
    int c = base & 127;
    float4 sc = *reinterpret_cast<const float4*>(ss + c);
    float4 sh = *reinterpret_cast<const float4*>(ss + C + c);
    float4 v  = *reinterpret_cast<const float4*>(x + base);
    float4 f  = *reinterpret_cast<const float4*>(feats + base);
    float4 o;
    o.x = fmaxf(fmaf(v.x, sc.x, sh.x) + f.x, 0.f);
    o.y = fmaxf(fmaf(v.y, sc.y, sh.y) + f.y, 0.f);
    o.z = fmaxf(fmaf(v.z, sc.z, sh.z) + f.z, 0.f);
    o.w = fmaxf(fmaf(v.w, sc.w, sh.w) + f.w, 0.f);
    *reinterpret_cast<float4*>(x + base) = o;
}

extern "C" void kernel_launch(void* const* d_in, const int* in_sizes, int n_in,
                              void* d_out, int out_size, void* d_ws, size_t ws_size,
                              hipStream_t stream) {
    const float* feats   = (const float*)d_in[0];
    const int* in_maps   = (const int*)d_in[1];
    const int* out_maps  = (const int*)d_in[2];
    const float* W1      = (const float*)d_in[3];
    const float* gamma1  = (const float*)d_in[4];
    const float* beta1   = (const float*)d_in[5];
    const float* W2      = (const float*)d_in[6];
    const float* gamma2  = (const float*)d_in[7];
    const float* beta2   = (const float*)d_in[8];
    float* out = (float*)d_out;

    char* ws = (char*)d_ws;
    uint16_t* featsB = (uint16_t*)(ws);                    // 67,108,864 B
    uint16_t* bn1B   = (uint16_t*)(ws + 67108864);         // 67,108,864 B
    uint16_t* WT1    = (uint16_t*)(ws + 134217728);        // 884,736 B
    uint16_t* WT2    = (uint16_t*)(ws + 135102464);        // 884,736 B
    float*    sums1  = (float*)   (ws + 135987200);        // 256 f32
    float*    sums2  = sums1 + 256;                        // 256 f32
    float*    ss1    = sums1 + 512;                        // 256 f32
    float*    ss2    = sums1 + 768;                        // 256 f32

    hipMemsetAsync(out, 0, (size_t)N * C * 4, stream);
    hipMemsetAsync(sums1, 0, 512 * 4, stream);             // sums1 + sums2

    cast_feats_kernel<<<N * C / 8 / 256, 256, 0, stream>>>(feats, featsB);
    transpose_w_kernel<<<K * C * C / 256, 256, 0, stream>>>(W1, W2, WT1, WT2);

    conv_kernel<<<K * TILES_PER_K, 256, 0, stream>>>(featsB, WT1, in_maps, out_maps, out);
    stats_kernel<<<1024, 256, 0, stream>>>(out, sums1);
    finalize_kernel<<<1, 128, 0, stream>>>(sums1, gamma1, beta1, ss1);
    bnrelu_kernel<<<N * C / 8 / 256, 256, 0, stream>>>(out, ss1, bn1B);

    hipMemsetAsync(out, 0, (size_t)N * C * 4, stream);
    conv_kernel<<<K * TILES_PER_K, 256, 0, stream>>>(bn1B, WT2, in_maps, out_maps, out);
    stats_kernel<<<1024, 256, 0, stream>>>(out, sums2);
    finalize_kernel<<<1, 128, 0, stream>>>(sums2, gamma2, beta2, ss2);
    final_kernel<<<N * C / 4 / 256, 256, 0, stream>>>(out, feats, ss2);
}

// Round 2
// 3394.997 us; speedup vs baseline: 1.0023x; 1.0023x over previous
//
#include <hip/hip_runtime.h>
#include <cstdint>

typedef __bf16  bf16x8  __attribute__((ext_vector_type(8)));
typedef short   short8v __attribute__((ext_vector_type(8)));
typedef float   f32x4   __attribute__((ext_vector_type(4)));

constexpr int N  = 262144;
constexpr int C  = 128;
constexpr int K  = 27;
constexpr int M  = 131072;
constexpr int KM = K * M;                 // 3,538,944
constexpr int BR = 64;                    // rows per conv block
constexpr int TILES_PER_K = M / BR;       // 2048

__device__ __forceinline__ uint16_t f2bf(float f) {
    union { float f; uint32_t u; } x; x.f = f;
    uint32_t r = (x.u + 0x7FFFu + ((x.u >> 16) & 1u)) >> 16;  // RNE
    return (uint16_t)r;
}
__device__ __forceinline__ float bf2f(uint16_t u) {
    union { uint32_t u; float f; } x; x.u = ((uint32_t)u) << 16;
    return x.f;
}

// ---------- prep: feats f32 -> bf16 ----------
__global__ __launch_bounds__(256) void cast_feats_kernel(
    const float* __restrict__ in, uint16_t* __restrict__ out) {
    int i = blockIdx.x * 256 + threadIdx.x;        // 8 elems per thread
    const float4* src = reinterpret_cast<const float4*>(in) + (size_t)i * 2;
    float4 a = src[0], b = src[1];
    union { uint16_t u[8]; short8v v; } r;
    r.u[0]=f2bf(a.x); r.u[1]=f2bf(a.y); r.u[2]=f2bf(a.z); r.u[3]=f2bf(a.w);
    r.u[4]=f2bf(b.x); r.u[5]=f2bf(b.y); r.u[6]=f2bf(b.z); r.u[7]=f2bf(b.w);
    *(reinterpret_cast<short8v*>(out) + i) = r.v;
}

// ---------- prep: W[k][cin][cout] f32 -> WT[k][cout][cin] bf16 (both convs) ----------
__global__ __launch_bounds__(256) void transpose_w_kernel(
    const float* __restrict__ W1, const float* __restrict__ W2,
    uint16_t* __restrict__ WT1, uint16_t* __restrict__ WT2) {
    int i = blockIdx.x * 256 + threadIdx.x;        // over K*C*C = 442368
    int k    = i / (C * C);
    int rem  = i - k * (C * C);
    int cout = rem >> 7;
    int cin  = rem & 127;
    int src  = k * C * C + cin * C + cout;
    WT1[i] = f2bf(W1[src]);
    WT2[i] = f2bf(W2[src]);
}

// ================= counting sort of (k,m) pairs by out index =================
__global__ __launch_bounds__(256) void hist_kernel(
    const int* __restrict__ out_maps, int* __restrict__ counts) {
    int i = blockIdx.x * 256 + threadIdx.x;
    atomicAdd(&counts[out_maps[i]], 1);
}

__global__ __launch_bounds__(256) void scan1_kernel(
    const int* __restrict__ counts, int* __restrict__ row_start, int* __restrict__ bsum) {
    __shared__ int lds[256];
    int t = threadIdx.x;
    int base = blockIdx.x * 1024 + t * 4;
    int4 c = *reinterpret_cast<const int4*>(counts + base);
    int tot = c.x + c.y + c.z + c.w;
    lds[t] = tot;
    __syncthreads();
    for (int off = 1; off < 256; off <<= 1) {
        int v = (t >= off) ? lds[t - off] : 0;
        __syncthreads();
        lds[t] += v;
        __syncthreads();
    }
    int excl = lds[t] - tot;
    int4 o;
    o.x = excl; o.y = excl + c.x; o.z = o.y + c.y; o.w = o.z + c.z;
    *reinterpret_cast<int4*>(row_start + base) = o;
    if (t == 255) bsum[blockIdx.x] = lds[255];
}

__global__ void scan2_kernel(int* __restrict__ bsum) {
    __shared__ int lds[256];
    int t = threadIdx.x;
    int v0 = bsum[t];
    lds[t] = v0;
    __syncthreads();
    for (int off = 1; off < 256; off <<= 1) {
        int v = (t >= off) ? lds[t - off] : 0;
        __syncthreads();
        lds[t] += v;
        __syncthreads();
    }
    bsum[t] = lds[t] - v0;   // exclusive
}

__global__ __launch_bounds__(256) void scan3_kernel(
    int* __restrict__ row_start, const int* __restrict__ bsum) {
    int i = blockIdx.x * 256 + threadIdx.x;
    row_start[i] += bsum[i >> 10];
    if (i == 0) row_start[N] = KM;
}

__global__ __launch_bounds__(256) void scatter_kernel(
    const int* __restrict__ out_maps, const int* __restrict__ row_start,
    int* __restrict__ cursor, int* __restrict__ posArr) {
    int i = blockIdx.x * 256 + threadIdx.x;
    int o = out_maps[i];
    int pos = row_start[o] + atomicAdd(&cursor[o], 1);
    posArr[i] = pos;
}

// ================= phase 1: gather + MFMA GEMM -> contrib (bf16, rank order) =================
__global__ __launch_bounds__(256, 3) void gemm_kernel(
    const uint16_t* __restrict__ featsB,   // [N][C] bf16
    const uint16_t* __restrict__ WT,       // [K][Cout][Cin] bf16
    const int* __restrict__ in_maps,       // [K][M]
    const int* __restrict__ posArr,        // [K*M] sorted rank
    uint16_t* __restrict__ contrib)        // [K*M][C] bf16, indexed by rank
{
    __shared__ char lds[BR * C * 2 + C * C * 2];   // A 16KB + W 32KB = 48KB
    char* Alds = lds;
    char* Wlds = lds + BR * C * 2;

    const int tile = blockIdx.x;
    const int k    = tile / TILES_PER_K;
    const int m0   = (tile % TILES_PER_K) * BR;
    const int tid  = threadIdx.x;

    {
        const int* im = in_maps + k * M + m0;
        #pragma unroll
        for (int i = 0; i < 4; ++i) {
            int chunk = tid + 256 * i;
            int row   = chunk >> 4;
            int c8    = chunk & 15;
            int g     = im[row];
            short8v v = *reinterpret_cast<const short8v*>(featsB + (size_t)g * C + c8 * 8);
            int off = (row * 256 + c8 * 16) ^ ((row & 7) << 4);
            *reinterpret_cast<short8v*>(Alds + off) = v;
        }
        const uint16_t* w = WT + k * C * C;
        #pragma unroll
        for (int i = 0; i < 8; ++i) {
            int chunk = tid + 256 * i;
            int cout  = chunk >> 4;
            int c8    = chunk & 15;
            short8v v = *reinterpret_cast<const short8v*>(w + chunk * 8);
            int off = (cout * 256 + c8 * 16) ^ ((cout & 7) << 4);
            *reinterpret_cast<short8v*>(Wlds + off) = v;
        }
    }
    __syncthreads();

    const int wave  = tid >> 6;
    const int lane  = tid & 63;
    const int r16   = lane & 15;
    const int khalf = lane >> 4;

    short8v a[4];
    {
        int row  = wave * 16 + r16;
        int base = row * 256;
        int swz  = (row & 7) << 4;
        #pragma unroll
        for (int kk = 0; kk < 4; ++kk)
            a[kk] = *reinterpret_cast<const short8v*>(Alds + ((base + kk * 64 + khalf * 16) ^ swz));
    }

    f32x4 acc[8];
    #pragma unroll
    for (int t = 0; t < 8; ++t) acc[t] = (f32x4){0.f, 0.f, 0.f, 0.f};

    #pragma unroll
    for (int t = 0; t < 8; ++t) {
        int col  = t * 16 + r16;
        int base = col * 256;
        int swz  = (col & 7) << 4;
        #pragma unroll
        for (int kk = 0; kk < 4; ++kk) {
            short8v b = *reinterpret_cast<const short8v*>(Wlds + ((base + kk * 64 + khalf * 16) ^ swz));
            acc[t] = __builtin_amdgcn_mfma_f32_16x16x32_bf16(
                __builtin_bit_cast(bf16x8, a[kk]), __builtin_bit_cast(bf16x8, b), acc[t], 0, 0, 0);
        }
    }

    // store: D layout col=lane&15 (=r16), row=(lane>>4)*4+j
    const int* pp = posArr + k * M + m0 + wave * 16 + khalf * 4;
    #pragma unroll
    for (int j = 0; j < 4; ++j) {
        int pos = pp[j];
        uint16_t* dst = contrib + (size_t)pos * C + r16;
        #pragma unroll
        for (int t = 0; t < 8; ++t)
            dst[t * 16] = f2bf(acc[t][j]);
    }
}

// ================= phase 2: segmented streaming reduce -> out (f32) =================
__global__ __launch_bounds__(256) void reduce_kernel(
    const uint16_t* __restrict__ contrib, const int* __restrict__ row_start,
    float* __restrict__ out) {
    const int tid    = threadIdx.x;
    const int lane16 = tid & 15;
    const int grp    = tid >> 4;
    #pragma unroll
    for (int rr = 0; rr < 4; ++rr) {
        int n = blockIdx.x * 64 + rr * 16 + grp;
        int s = row_start[n], e = row_start[n + 1];
        float acc[8] = {0.f,0.f,0.f,0.f,0.f,0.f,0.f,0.f};
        for (int j = s; j < e; ++j) {
            short8v v = *reinterpret_cast<const short8v*>(contrib + (size_t)j * C + lane16 * 8);
            #pragma unroll
            for (int i = 0; i < 8; ++i) acc[i] += bf2f((uint16_t)(unsigned short)v[i]);
        }
        float* dst = out + (size_t)n * C + lane16 * 8;
        float4 o0 = {acc[0], acc[1], acc[2], acc[3]};
        float4 o1 = {acc[4], acc[5], acc[6], acc[7]};
        *reinterpret_cast<float4*>(dst)     = o0;
        *reinterpret_cast<float4*>(dst + 4) = o1;
    }
}

// ================= fallback conv (atomic scatter) =================
__global__ __launch_bounds__(256, 3) void conv_kernel(
    const uint16_t* __restrict__ featsB,
    const uint16_t* __restrict__ WT,
    const int* __restrict__ in_maps,
    const int* __restrict__ out_maps,
    float* __restrict__ out)
{
    __shared__ char lds[BR * C * 2 + C * C * 2];
    char* Alds = lds;
    char* Wlds = lds + BR * C * 2;

    const int tile = blockIdx.x;
    const int k    = tile / TILES_PER_K;
    const int m0   = (tile % TILES_PER_K) * BR;
    const int tid  = threadIdx.x;

    {
        const int* im = in_maps + k * M + m0;
        #pragma unroll
        for (int i = 0; i < 4; ++i) {
            int chunk = tid + 256 * i;
            int row   = chunk >> 4;
            int c8    = chunk & 15;
            int g     = im[row];
            short8v v = *reinterpret_cast<const short8v*>(featsB + (size_t)g * C + c8 * 8);
            int off = (row * 256 + c8 * 16) ^ ((row & 7) << 4);
            *reinterpret_cast<short8v*>(Alds + off) = v;
        }
        const uint16_t* w = WT + k * C * C;
        #pragma unroll
        for (int i = 0; i < 8; ++i) {
            int chunk = tid + 256 * i;
            int cout  = chunk >> 4;
            int c8    = chunk & 15;
            short8v v = *reinterpret_cast<const short8v*>(w + chunk * 8);
            int off = (cout * 256 + c8 * 16) ^ ((cout & 7) << 4);
            *reinterpret_cast<short8v*>(Wlds + off) = v;
        }
    }
    __syncthreads();

    const int wave  = tid >> 6;
    const int lane  = tid & 63;
    const int r16   = lane & 15;
    const int khalf = lane >> 4;

    short8v a[4];
    {
        int row  = wave * 16 + r16;
        int base = row * 256;
        int swz  = (row & 7) << 4;
        #pragma unroll
        for (int kk = 0; kk < 4; ++kk)
            a[kk] = *reinterpret_cast<const short8v*>(Alds + ((base + kk * 64 + khalf * 16) ^ swz));
    }

    f32x4 acc[8];
    #pragma unroll
    for (int t = 0; t < 8; ++t) acc[t] = (f32x4){0.f, 0.f, 0.f, 0.f};

    #pragma unroll
    for (int t = 0; t < 8; ++t) {
        int col  = t * 16 + r16;
        int base = col * 256;
        int swz  = (col & 7) << 4;
        #pragma unroll
        for (int kk = 0; kk < 4; ++kk) {
            short8v b = *reinterpret_cast<const short8v*>(Wlds + ((base + kk * 64 + khalf * 16) ^ swz));
            acc[t] = __builtin_amdgcn_mfma_f32_16x16x32_bf16(
                __builtin_bit_cast(bf16x8, a[kk]), __builtin_bit_cast(bf16x8, b), acc[t], 0, 0, 0);
        }
    }

    const int* om = out_maps + k * M + m0 + wave * 16;
    #pragma unroll
    for (int j = 0; j < 4; ++j) {
        int g = om[khalf * 4 + j];
        float* dst = out + (size_t)g * C + r16;
        #pragma unroll
        for (int t = 0; t < 8; ++t)
            unsafeAtomicAdd(dst + t * 16, acc[t][j]);
    }
}

// ---------- per-channel sum & sumsq ----------
__global__ __launch_bounds__(256) void stats_kernel(
    const float* __restrict__ x, float* __restrict__ sums) {
    const int tid = threadIdx.x;
    const int c32 = tid & 31;
    const int rg  = tid >> 5;
    constexpr int RPB = N / 1024;       // 256 rows per block
    float4 s = {0,0,0,0}, q = {0,0,0,0};
    const float* base = x + (size_t)blockIdx.x * RPB * C + c32 * 4;
    for (int r = rg; r < RPB; r += 8) {
        float4 v = *reinterpret_cast<const float4*>(base + r * C);
        s.x += v.x; s.y += v.y; s.z += v.z; s.w += v.w;
        q.x += v.x*v.x; q.y += v.y*v.y; q.z += v.z*v.z; q.w += v.w*v.w;
    }
    __shared__ float4 red[8][32];
    red[rg][c32] = s;
    __syncthreads();
    if (rg == 0) {
        float4 t = red[0][c32];
        #pragma unroll
        for (int j = 1; j < 8; ++j) { float4 u = red[j][c32]; t.x+=u.x; t.y+=u.y; t.z+=u.z; t.w+=u.w; }
        unsafeAtomicAdd(&sums[c32*4+0], t.x); unsafeAtomicAdd(&sums[c32*4+1], t.y);
        unsafeAtomicAdd(&sums[c32*4+2], t.z); unsafeAtomicAdd(&sums[c32*4+3], t.w);
    }
    __syncthreads();
    red[rg][c32] = q;
    __syncthreads();
    if (rg == 0) {
        float4 t = red[0][c32];
        #pragma unroll
        for (int j = 1; j < 8; ++j) { float4 u = red[j][c32]; t.x+=u.x; t.y+=u.y; t.z+=u.z; t.w+=u.w; }
        unsafeAtomicAdd(&sums[C+c32*4+0], t.x); unsafeAtomicAdd(&sums[C+c32*4+1], t.y);
        unsafeAtomicAdd(&sums[C+c32*4+2], t.z); unsafeAtomicAdd(&sums[C+c32*4+3], t.w);
    }
}

__global__ void finalize_kernel(const float* __restrict__ sums,
                                const float* __restrict__ gamma, const float* __restrict__ beta,
                                float* __restrict__ ss) {
    int c = threadIdx.x;
    float m  = sums[c] * (1.0f / N);
    float v  = sums[C + c] * (1.0f / N) - m * m;
    float r  = rsqrtf(v + 1e-5f);
    float sc = gamma[c] * r;
    ss[c]     = sc;
    ss[C + c] = beta[c] - m * sc;
}

__global__ __launch_bounds__(256) void bnrelu_kernel(
    const float* __restrict__ x, const float* __restrict__ ss, uint16_t* __restrict__ out) {
    int i = blockIdx.x * 256 + threadIdx.x;
    int base = i * 8;
    int c = base & 127;
    float4 sc0 = *reinterpret_cast<const float4*>(ss + c);
    float4 sc1 = *reinterpret_cast<const float4*>(ss + c + 4);
    float4 sh0 = *reinterpret_cast<const float4*>(ss + C + c);
    float4 sh1 = *reinterpret_cast<const float4*>(ss + C + c + 4);
    const float4* src = reinterpret_cast<const float4*>(x + base);
    float4 a = src[0], b = src[1];
    union { uint16_t u[8]; short8v v; } r;
    r.u[0] = f2bf(fmaxf(fmaf(a.x, sc0.x, sh0.x), 0.f));
    r.u[1] = f2bf(fmaxf(fmaf(a.y, sc0.y, sh0.y), 0.f));
    r.u[2] = f2bf(fmaxf(fmaf(a.z, sc0.z, sh0.z), 0.f));
    r.u[3] = f2bf(fmaxf(fmaf(a.w, sc0.w, sh0.w), 0.f));
    r.u[4] = f2bf(fmaxf(fmaf(b.x, sc1.x, sh1.x), 0.f));
    r.u[5] = f2bf(fmaxf(fmaf(b.y, sc1.y, sh1.y), 0.f));
    r.u[6] = f2bf(fmaxf(fmaf(b.z, sc1.z, sh1.z), 0.f));
    r.u[7] = f2bf(fmaxf(fmaf(b.w, sc1.w, sh1.w), 0.f));
    *(reinterpret_cast<short8v*>(out) + i) = r.v;
}

__global__ __launch_bounds__(256) void final_kernel(
    float* __restrict__ x, const float* __restrict__ feats, const float* __restrict__ ss) {
    int i = blockIdx.x * 256 + threadIdx.x;
    int base = i * 4;
    int c = base & 127;
    float4 sc = *reinterpret_cast<const float4*>(ss + c);
    float4 sh = *reinterpret_cast<const float4*>(ss + C + c);
    float4 v  = *reinterpret_cast<const float4*>(x + base);
    float4 f  = *reinterpret_cast<const float4*>(feats + base);
    float4 o;
    o.x = fmaxf(fmaf(v.x, sc.x, sh.x) + f.x, 0.f);
    o.y = fmaxf(fmaf(v.y, sc.y, sh.y) + f.y, 0.f);
    o.z = fmaxf(fmaf(v.z, sc.z, sh.z) + f.z, 0.f);
    o.w = fmaxf(fmaf(v.w, sc.w, sh.w) + f.w, 0.f);
    *reinterpret_cast<float4*>(x + base) = o;
}

extern "C" void kernel_launch(void* const* d_in, const int* in_sizes, int n_in,
                              void* d_out, int out_size, void* d_ws, size_t ws_size,
                              hipStream_t stream) {
    const float* feats   = (const float*)d_in[0];
    const int* in_maps   = (const int*)d_in[1];
    const int* out_maps  = (const int*)d_in[2];
    const float* W1      = (const float*)d_in[3];
    const float* gamma1  = (const float*)d_in[4];
    const float* beta1   = (const float*)d_in[5];
    const float* W2      = (const float*)d_in[6];
    const float* gamma2  = (const float*)d_in[7];
    const float* beta2   = (const float*)d_in[8];
    float* out = (float*)d_out;

    char* ws = (char*)d_ws;

    // ---- fast path layout (~993 MB) ----
    size_t off = 0;
    auto alloc = [&](size_t bytes) { size_t o = off; off = (off + bytes + 255) & ~(size_t)255; return o; };
    size_t o_contrib  = alloc((size_t)KM * C * 2);      // 905,969,664
    size_t o_featsB   = alloc((size_t)N * C * 2);       // 67,108,864 (bn1B aliases this)
    size_t o_WT1      = alloc((size_t)K * C * C * 2);
    size_t o_WT2      = alloc((size_t)K * C * C * 2);
    size_t o_posArr   = alloc((size_t)KM * 4);
    size_t o_rowstart = alloc((size_t)(N + 1) * 4);
    size_t o_counts   = alloc((size_t)N * 4);
    size_t o_cursor   = alloc((size_t)N * 4);
    size_t o_bsum     = alloc(1024);
    size_t o_sums     = alloc(4096);
    size_t need_fast  = off;

    if (ws_size >= need_fast) {
        uint16_t* contrib   = (uint16_t*)(ws + o_contrib);
        uint16_t* featsB    = (uint16_t*)(ws + o_featsB);
        uint16_t* bn1B      = featsB;                   // alias: lifetimes disjoint
        uint16_t* WT1       = (uint16_t*)(ws + o_WT1);
        uint16_t* WT2       = (uint16_t*)(ws + o_WT2);
        int*      posArr    = (int*)(ws + o_posArr);
        int*      row_start = (int*)(ws + o_rowstart);
        int*      counts    = (int*)(ws + o_counts);
        int*      cursor    = (int*)(ws + o_cursor);
        int*      bsum      = (int*)(ws + o_bsum);
        float*    sums1     = (float*)(ws + o_sums);
        float*    sums2     = sums1 + 256;
        float*    ss1       = sums1 + 512;
        float*    ss2       = sums1 + 768;

        hipMemsetAsync(counts, 0, (size_t)N * 4, stream);
        hipMemsetAsync(cursor, 0, (size_t)N * 4, stream);
        hipMemsetAsync(sums1, 0, 512 * 4, stream);

        cast_feats_kernel<<<N * C / 8 / 256, 256, 0, stream>>>(feats, featsB);
        transpose_w_kernel<<<K * C * C / 256, 256, 0, stream>>>(W1, W2, WT1, WT2);

        // counting sort of pairs by output row (shared by both convs)
        hist_kernel<<<KM / 256, 256, 0, stream>>>(out_maps, counts);
        scan1_kernel<<<N / 1024, 256, 0, stream>>>(counts, row_start, bsum);
        scan2_kernel<<<1, 256, 0, stream>>>(bsum);
        scan3_kernel<<<N / 256, 256, 0, stream>>>(row_start, bsum);
        scatter_kernel<<<KM / 256, 256, 0, stream>>>(out_maps, row_start, cursor, posArr);

        // conv1
        gemm_kernel<<<K * TILES_PER_K, 256, 0, stream>>>(featsB, WT1, in_maps, posArr, contrib);
        reduce_kernel<<<N / 64, 256, 0, stream>>>(contrib, row_start, out);
        stats_kernel<<<1024, 256, 0, stream>>>(out, sums1);
        finalize_kernel<<<1, 128, 0, stream>>>(sums1, gamma1, beta1, ss1);
        bnrelu_kernel<<<N * C / 8 / 256, 256, 0, stream>>>(out, ss1, bn1B);

        // conv2
        gemm_kernel<<<K * TILES_PER_K, 256, 0, stream>>>(bn1B, WT2, in_maps, posArr, contrib);
        reduce_kernel<<<N / 64, 256, 0, stream>>>(contrib, row_start, out);
        stats_kernel<<<1024, 256, 0, stream>>>(out, sums2);
        finalize_kernel<<<1, 128, 0, stream>>>(sums2, gamma2, beta2, ss2);
        final_kernel<<<N * C / 4 / 256, 256, 0, stream>>>(out, feats, ss2);
        return;
    }

    // ---- fallback: atomic-scatter version (passed round 1) ----
    uint16_t* featsB = (uint16_t*)(ws);
    uint16_t* bn1B   = (uint16_t*)(ws + 67108864);
    uint16_t* WT1    = (uint16_t*)(ws + 134217728);
    uint16_t* WT2    = (uint16_t*)(ws + 135102464);
    float*    sums1  = (float*)   (ws + 135987200);
    float*    sums2  = sums1 + 256;
    float*    ss1    = sums1 + 512;
    float*    ss2    = sums1 + 768;

    hipMemsetAsync(out, 0, (size_t)N * C * 4, stream);
    hipMemsetAsync(sums1, 0, 512 * 4, stream);

    cast_feats_kernel<<<N * C / 8 / 256, 256, 0, stream>>>(feats, featsB);
    transpose_w_kernel<<<K * C * C / 256, 256, 0, stream>>>(W1, W2, WT1, WT2);

    conv_kernel<<<K * TILES_PER_K, 256, 0, stream>>>(featsB, WT1, in_maps, out_maps, out);
    stats_kernel<<<1024, 256, 0, stream>>>(out, sums1);
    finalize_kernel<<<1, 128, 0, stream>>>(sums1, gamma1, beta1, ss1);
    bnrelu_kernel<<<N * C / 8 / 256, 256, 0, stream>>>(out, ss1, bn1B);

    hipMemsetAsync(out, 0, (size_t)N * C * 4, stream);
    conv_kernel<<<K * TILES_PER_K, 256, 0, stream>>>(bn1B, WT2, in_maps, out_maps, out);
    stats_kernel<<<1024, 256, 0, stream>>>(out, sums2);
    finalize_kernel<<<1, 128, 0, stream>>>(sums2, gamma2, beta2, ss2);
    final_kernel<<<N * C / 4 / 256, 256, 0, stream>>>(out, feats, ss2);
}